// Round 4
// baseline (87.887 us; speedup 1.0000x reference)
//
#include <hip/hip_runtime.h>
#include <math.h>

#define MAX_SHIFT 128
#define S_TOTAL   257
#define SGB       9                    // shifts per block
#define NSB       29                   // ceil(257/9) -> 232 blocks = NSB*BC <= 256 CUs (no tail)
#define BLOCK     1024                 // 16 waves = 4 waves/SIMD for latency hiding
#define TY        8192                 // time-chunk staged in LDS
#define VY        8                    // consecutive y elems per thread per chunk
#define XT        8208                 // TY + 16, covers max rel index 8203
#define NQ        (SGB + 4)            // reduction quantities: 9 cross + Sx,Sxx,Sy,Syy

// One block = one (shift-group, bc), fully independent. Single dispatch, no
// workspace, no atomics. Block computes its 9 cross sums, the global sums,
// edge corrections, and writes 9 outputs.
//
// Alignment trick: staged-window base is d0 rounded DOWN to a multiple of 4
// (d0r), so all global float4 loads and LDS float4 accesses stay 16B-aligned;
// the residual shift delta = d0 - d0r (0..3) is applied in the 20-float
// register window.
__global__ __launch_bounds__(BLOCK) void spc_kernel(const float* __restrict__ x,
                                                    const float* __restrict__ y,
                                                    float* __restrict__ out,
                                                    int T, int BC) {
    const int sg    = blockIdx.x;          // shift group: s in [sg*9, sg*9+9)
    const int bc    = blockIdx.y;
    const int s0    = sg * SGB;
    const int d0    = s0 - MAX_SHIFT;
    const int d0r   = d0 & ~3;             // floor to multiple of 4 (works for negatives)
    const int delta = d0 - d0r;            // 0..3
    const int tid   = threadIdx.x;
    const float* xb = x + (size_t)bc * T;
    const float* yb = y + (size_t)bc * T;
    const int NCH = T / TY;                // 4

    __shared__ __align__(16) float xs[XT];
    __shared__ float red[NQ][16];          // per-wave partials
    __shared__ float tot[NQ];
    __shared__ float edge[SGB][2];         // per-s (pw, pw2) edge sums

    float acc[SGB];
#pragma unroll
    for (int j = 0; j < SGB; ++j) acc[j] = 0.f;
    float sx = 0.f, sxx = 0.f, sy = 0.f, syy = 0.f;

    for (int c = 0; c < NCH; ++c) {
        const int t0 = c * TY;
        const int G0 = t0 + d0r;           // global x index of xs[0]; multiple of 4

        __syncthreads();                   // protect xs from previous chunk's readers
        // stage x window [G0, G0 + XT) with zero-fill outside [0, T)
        for (int ls = tid * 4; ls < XT; ls += BLOCK * 4) {
            int g = G0 + ls;
            float4 v;
            if (g >= 0 && g + 3 < T) {
                v = *(const float4*)(xb + g);
            } else {
                float tmp[4];
#pragma unroll
                for (int e = 0; e < 4; ++e) {
                    int gg = g + e;
                    tmp[e] = (gg >= 0 && gg < T) ? xb[gg] : 0.f;
                }
                v = make_float4(tmp[0], tmp[1], tmp[2], tmp[3]);
            }
            *(float4*)(xs + ls) = v;
        }
        __syncthreads();

        // one vector iter per chunk: b = tid*8 covers all of TY
        {
            const int b = tid * VY;        // multiple of 8
            const int t = t0 + b;
            float yv[VY], xv[VY], xw[20];
            *(float4*)(yv)     = *(const float4*)(yb + t);
            *(float4*)(yv + 4) = *(const float4*)(yb + t + 4);
            *(float4*)(xv)     = *(const float4*)(xb + t);      // for sums (L1/L2-hot)
            *(float4*)(xv + 4) = *(const float4*)(xb + t + 4);
#pragma unroll
            for (int i = 0; i < 5; ++i)
                *(float4*)(xw + 4 * i) = *(const float4*)(xs + b + 4 * i);

#pragma unroll
            for (int e = 0; e < VY; ++e) {
                const float yvv = yv[e];
#pragma unroll
                for (int j = 0; j < SGB; ++j)
                    acc[j] = fmaf(xw[delta + e + j], yvv, acc[j]);
                sy += yvv; syy = fmaf(yvv, yvv, syy);
                sx += xv[e]; sxx = fmaf(xv[e], xv[e], sxx);
            }
        }
    }

    // ---- wave-level reductions ----
    const int lane = tid & 63, wave = tid >> 6;
#pragma unroll
    for (int j = 0; j < SGB; ++j) {
        float v = acc[j];
        for (int off = 32; off; off >>= 1) v += __shfl_down(v, off, 64);
        if (lane == 0) red[j][wave] = v;
    }
    {
        float v4[4] = {sx, sxx, sy, syy};
#pragma unroll
        for (int q = 0; q < 4; ++q) {
            float v = v4[q];
            for (int off = 32; off; off >>= 1) v += __shfl_down(v, off, 64);
            if (lane == 0) red[SGB + q][wave] = v;
        }
    }

    // ---- edge corrections: wave w handles local shift sl = w (w < 9) ----
    if (wave < SGB) {
        const int sl = wave;
        int d = d0 + sl;
        float pw = 0.f, pw2 = 0.f;
        if (d > 0) {
            for (int j = lane; j < d; j += 64)  { float v = xb[j];         pw += v; pw2 = fmaf(v, v, pw2); }
        } else if (d < 0) {
            for (int j = lane; j < -d; j += 64) { float v = xb[T + d + j]; pw += v; pw2 = fmaf(v, v, pw2); }
        }
        for (int off = 32; off; off >>= 1) {
            pw  += __shfl_down(pw,  off, 64);
            pw2 += __shfl_down(pw2, off, 64);
        }
        if (lane == 0) { edge[sl][0] = pw; edge[sl][1] = pw2; }
    }
    __syncthreads();

    // ---- combine per-wave partials ----
    if (tid < NQ) {
        float v = 0.f;
#pragma unroll
        for (int w = 0; w < 16; ++w) v += red[tid][w];
        tot[tid] = v;
    }
    __syncthreads();

    // ---- finalize: 9 outputs per block ----
    if (tid < SGB) {
        int s = s0 + tid;
        if (s < S_TOTAL) {
            float cr  = tot[tid];
            float Sx  = tot[SGB + 0];
            float Sxx = tot[SGB + 1];
            float Sy  = tot[SGB + 2];
            float Syy = tot[SGB + 3];
            float Sw  = Sx  - edge[tid][0];
            float Sw2 = Sxx - edge[tid][1];
            float invT  = 1.0f / (float)T;
            float corr  = cr  - Sw * Sy * invT;
            float normx = Sw2 - Sw * Sw * invT;
            float normy = Syy - Sy * Sy * invT;
            out[(size_t)s * BC + bc] = corr / sqrtf(normx * normy);
        }
    }
}

extern "C" void kernel_launch(void* const* d_in, const int* in_sizes, int n_in,
                              void* d_out, int out_size, void* d_ws, size_t ws_size,
                              hipStream_t stream) {
    const float* x = (const float*)d_in[0];
    const float* y = (const float*)d_in[1];
    float* out = (float*)d_out;

    const int BC = out_size / S_TOTAL;   // 8
    const int T  = in_sizes[0] / BC;     // 32768

    dim3 grid(NSB, BC);                  // 29 x 8 = 232 blocks <= 256 CUs
    spc_kernel<<<grid, BLOCK, 0, stream>>>(x, y, out, T, BC);
}

// Round 5
// 69.146 us; speedup vs baseline: 1.2710x; 1.2710x over previous
//
#include <hip/hip_runtime.h>
#include <math.h>

#define MAX_SHIFT 128
#define S_TOTAL   257
#define SGB       8                    // shifts per block (keeps all reg indices compile-time)
#define NSB       33                   // 33*8 = 264 >= 257 shift slots
#define BLOCK     512                  // 8 waves/block
#define VY        8                    // consecutive t-elements per thread per iter
#define NW        (BLOCK / 64)         // waves per block
#define NQ        (SGB + 4)            // 8 cross + Sx,Sxx,Sy,Syy

// One block = one (shift-group, bc), fully independent; single dispatch, no
// atomics, no workspace. NO LDS staging: x/y are 2 MB total -> fully
// L2-resident; window loads are coalesced float4, so we stream straight from
// global with zero barriers in the main loop.
__global__ __launch_bounds__(BLOCK) void spc_kernel(const float* __restrict__ x,
                                                    const float* __restrict__ y,
                                                    float* __restrict__ out,
                                                    int T, int BC) {
    const int sg  = blockIdx.x;            // shift group: s in [sg*8, sg*8+8)
    const int bc  = blockIdx.y;
    const int s0  = sg * SGB;
    const int d0  = s0 - MAX_SHIFT;        // multiple of 8 -> 16B-aligned windows
    const int tid = threadIdx.x;
    const float* xb = x + (size_t)bc * T;
    const float* yb = y + (size_t)bc * T;

    float acc[SGB];
#pragma unroll
    for (int j = 0; j < SGB; ++j) acc[j] = 0.f;
    float sx = 0.f, sxx = 0.f, sy = 0.f, syy = 0.f;

    // main loop: each thread owns strided 8-element t-segments
    for (int t = tid * VY; t < T; t += BLOCK * VY) {
        float yv[VY], xv[VY], xw[VY + SGB];   // 16-float x window
        *(float4*)(yv)     = *(const float4*)(yb + t);
        *(float4*)(yv + 4) = *(const float4*)(yb + t + 4);
        *(float4*)(xv)     = *(const float4*)(xb + t);
        *(float4*)(xv + 4) = *(const float4*)(xb + t + 4);

        const int g0 = t + d0;
        if (g0 >= 0 && g0 + 16 <= T) {        // interior: 4 aligned float4 loads
#pragma unroll
            for (int i = 0; i < 4; ++i)
                *(float4*)(xw + 4 * i) = *(const float4*)(xb + g0 + 4 * i);
        } else {                              // boundary: guarded scalar loads
#pragma unroll
            for (int i = 0; i < VY + SGB; ++i) {
                int g = g0 + i;
                xw[i] = (g >= 0 && g < T) ? xb[g] : 0.f;
            }
        }

#pragma unroll
        for (int e = 0; e < VY; ++e) {
            const float yvv = yv[e];
#pragma unroll
            for (int j = 0; j < SGB; ++j)
                acc[j] = fmaf(xw[e + j], yvv, acc[j]);   // all indices compile-time
            sy += yvv;  syy = fmaf(yvv, yvv, syy);
            sx += xv[e]; sxx = fmaf(xv[e], xv[e], sxx);
        }
    }

    // ---- wave-level reductions ----
    __shared__ float red[NQ][NW];
    __shared__ float tot[NQ];
    __shared__ float edge[SGB][2];
    const int lane = tid & 63, wave = tid >> 6;
#pragma unroll
    for (int j = 0; j < SGB; ++j) {
        float v = acc[j];
        for (int off = 32; off; off >>= 1) v += __shfl_down(v, off, 64);
        if (lane == 0) red[j][wave] = v;
    }
    {
        float v4[4] = {sx, sxx, sy, syy};
#pragma unroll
        for (int q = 0; q < 4; ++q) {
            float v = v4[q];
            for (int off = 32; off; off >>= 1) v += __shfl_down(v, off, 64);
            if (lane == 0) red[SGB + q][wave] = v;
        }
    }

    // ---- edge corrections: wave w handles local shift sl = w (NW == SGB) ----
    {
        const int sl = wave;
        int d = d0 + sl;
        float pw = 0.f, pw2 = 0.f;
        if (d > 0) {
            for (int j = lane; j < d; j += 64)  { float v = xb[j];         pw += v; pw2 = fmaf(v, v, pw2); }
        } else if (d < 0) {
            for (int j = lane; j < -d; j += 64) { float v = xb[T + d + j]; pw += v; pw2 = fmaf(v, v, pw2); }
        }
        for (int off = 32; off; off >>= 1) {
            pw  += __shfl_down(pw,  off, 64);
            pw2 += __shfl_down(pw2, off, 64);
        }
        if (lane == 0) { edge[sl][0] = pw; edge[sl][1] = pw2; }
    }
    __syncthreads();

    // ---- combine per-wave partials ----
    if (tid < NQ) {
        float v = 0.f;
#pragma unroll
        for (int w = 0; w < NW; ++w) v += red[tid][w];
        tot[tid] = v;
    }
    __syncthreads();

    // ---- finalize: 8 outputs per block ----
    if (tid < SGB) {
        int s = s0 + tid;
        if (s < S_TOTAL) {
            float cr  = tot[tid];
            float Sx  = tot[SGB + 0];
            float Sxx = tot[SGB + 1];
            float Sy  = tot[SGB + 2];
            float Syy = tot[SGB + 3];
            float Sw  = Sx  - edge[tid][0];
            float Sw2 = Sxx - edge[tid][1];
            float invT  = 1.0f / (float)T;
            float corr  = cr  - Sw * Sy * invT;
            float normx = Sw2 - Sw * Sw * invT;
            float normy = Syy - Sy * Sy * invT;
            out[(size_t)s * BC + bc] = corr / sqrtf(normx * normy);
        }
    }
}

extern "C" void kernel_launch(void* const* d_in, const int* in_sizes, int n_in,
                              void* d_out, int out_size, void* d_ws, size_t ws_size,
                              hipStream_t stream) {
    const float* x = (const float*)d_in[0];
    const float* y = (const float*)d_in[1];
    float* out = (float*)d_out;

    const int BC = out_size / S_TOTAL;   // 8
    const int T  = in_sizes[0] / BC;     // 32768

    dim3 grid(NSB, BC);                  // 33 x 8 = 264 blocks
    spc_kernel<<<grid, BLOCK, 0, stream>>>(x, y, out, T, BC);
}

// Round 6
// 65.671 us; speedup vs baseline: 1.3383x; 1.0529x over previous
//
#include <hip/hip_runtime.h>
#include <math.h>

#define MAX_SHIFT 128
#define S_TOTAL   257
#define SGB       9                    // shifts per block: s in [8*sg, 8*sg+8] (overlap by 1)
#define NSB       32                   // 32 groups x 8 bc = 256 blocks == 256 CUs, no tail
#define BLOCK     1024                 // 16 waves = 4 waves/SIMD
#define VY        8                    // consecutive t-elements per thread per iter
#define NW        (BLOCK / 64)         // 16 waves per block
#define NQ        (SGB + 4)            // 9 cross + Sx,Sxx,Sy,Syy

// One block = one (shift-group, bc), fully independent; single dispatch, no
// atomics, no workspace, no LDS staging (2 MB inputs are L2-resident; window
// loads are coalesced float4). Blocks sg and sg+1 both compute shift s=8sg+8;
// the FMA chains are bitwise identical (same thread partition and order), so
// the duplicate out-writes store identical bits -- benign race.
// Window: 9 shifts x 8 elems needs exactly 16 floats = 4 aligned float4 loads
// (d0 = 8*sg - 128 keeps 16B alignment; all register indices compile-time).
__global__ __launch_bounds__(BLOCK) void spc_kernel(const float* __restrict__ x,
                                                    const float* __restrict__ y,
                                                    float* __restrict__ out,
                                                    int T, int BC) {
    const int sg  = blockIdx.x;            // shift group
    const int bc  = blockIdx.y;
    const int s0  = sg * 8;                // first shift of this block
    const int d0  = s0 - MAX_SHIFT;        // multiple of 8 -> 16B-aligned windows
    const int tid = threadIdx.x;
    const float* xb = x + (size_t)bc * T;
    const float* yb = y + (size_t)bc * T;

    float acc[SGB];
#pragma unroll
    for (int j = 0; j < SGB; ++j) acc[j] = 0.f;
    float sx = 0.f, sxx = 0.f, sy = 0.f, syy = 0.f;

    // main loop: each thread owns strided 8-element t-segments (4 iters)
    for (int t = tid * VY; t < T; t += BLOCK * VY) {
        float yv[VY], xv[VY], xw[16];      // 16-float x window covers e+j in [0,16)
        *(float4*)(yv)     = *(const float4*)(yb + t);
        *(float4*)(yv + 4) = *(const float4*)(yb + t + 4);
        *(float4*)(xv)     = *(const float4*)(xb + t);
        *(float4*)(xv + 4) = *(const float4*)(xb + t + 4);

        const int g0 = t + d0;
        if (g0 >= 0 && g0 + 16 <= T) {     // interior: 4 aligned float4 loads
#pragma unroll
            for (int i = 0; i < 4; ++i)
                *(float4*)(xw + 4 * i) = *(const float4*)(xb + g0 + 4 * i);
        } else {                           // boundary: guarded scalar loads
#pragma unroll
            for (int i = 0; i < 16; ++i) {
                int g = g0 + i;
                xw[i] = (g >= 0 && g < T) ? xb[g] : 0.f;
            }
        }

#pragma unroll
        for (int e = 0; e < VY; ++e) {
            const float yvv = yv[e];
#pragma unroll
            for (int j = 0; j < SGB; ++j)
                acc[j] = fmaf(xw[e + j], yvv, acc[j]);   // compile-time indices
            sy += yvv;  syy = fmaf(yvv, yvv, syy);
            sx += xv[e]; sxx = fmaf(xv[e], xv[e], sxx);
        }
    }

    // ---- wave-level reductions ----
    __shared__ float red[NQ][NW];
    __shared__ float tot[NQ];
    __shared__ float edge[SGB][2];
    const int lane = tid & 63, wave = tid >> 6;
#pragma unroll
    for (int j = 0; j < SGB; ++j) {
        float v = acc[j];
        for (int off = 32; off; off >>= 1) v += __shfl_down(v, off, 64);
        if (lane == 0) red[j][wave] = v;
    }
    {
        float v4[4] = {sx, sxx, sy, syy};
#pragma unroll
        for (int q = 0; q < 4; ++q) {
            float v = v4[q];
            for (int off = 32; off; off >>= 1) v += __shfl_down(v, off, 64);
            if (lane == 0) red[SGB + q][wave] = v;
        }
    }

    // ---- edge corrections: waves 0..8 each handle one local shift ----
    if (wave < SGB) {
        const int sl = wave;
        int d = d0 + sl;
        float pw = 0.f, pw2 = 0.f;
        if (d > 0) {
            for (int j = lane; j < d; j += 64)  { float v = xb[j];         pw += v; pw2 = fmaf(v, v, pw2); }
        } else if (d < 0) {
            for (int j = lane; j < -d; j += 64) { float v = xb[T + d + j]; pw += v; pw2 = fmaf(v, v, pw2); }
        }
        for (int off = 32; off; off >>= 1) {
            pw  += __shfl_down(pw,  off, 64);
            pw2 += __shfl_down(pw2, off, 64);
        }
        if (lane == 0) { edge[sl][0] = pw; edge[sl][1] = pw2; }
    }
    __syncthreads();

    // ---- combine per-wave partials ----
    if (tid < NQ) {
        float v = 0.f;
#pragma unroll
        for (int w = 0; w < NW; ++w) v += red[tid][w];
        tot[tid] = v;
    }
    __syncthreads();

    // ---- finalize: 9 outputs per block (s = 8sg .. 8sg+8) ----
    if (tid < SGB) {
        int s = s0 + tid;
        if (s < S_TOTAL) {
            float cr  = tot[tid];
            float Sx  = tot[SGB + 0];
            float Sxx = tot[SGB + 1];
            float Sy  = tot[SGB + 2];
            float Syy = tot[SGB + 3];
            float Sw  = Sx  - edge[tid][0];
            float Sw2 = Sxx - edge[tid][1];
            float invT  = 1.0f / (float)T;
            float corr  = cr  - Sw * Sy * invT;
            float normx = Sw2 - Sw * Sw * invT;
            float normy = Syy - Sy * Sy * invT;
            out[(size_t)s * BC + bc] = corr / sqrtf(normx * normy);
        }
    }
}

extern "C" void kernel_launch(void* const* d_in, const int* in_sizes, int n_in,
                              void* d_out, int out_size, void* d_ws, size_t ws_size,
                              hipStream_t stream) {
    const float* x = (const float*)d_in[0];
    const float* y = (const float*)d_in[1];
    float* out = (float*)d_out;

    const int BC = out_size / S_TOTAL;   // 8
    const int T  = in_sizes[0] / BC;     // 32768

    dim3 grid(NSB, BC);                  // 32 x 8 = 256 blocks == 256 CUs
    spc_kernel<<<grid, BLOCK, 0, stream>>>(x, y, out, T, BC);
}